// Round 1
// baseline (698.965 us; speedup 1.0000x reference)
//
#include <hip/hip_runtime.h>

// out[b,k,p] = bias[k] + sum_{c in group k} w[c] * in[b,c,p]
// B=8, C=64, K=12, P=512*512. Pure streaming, memory-bound (~638 MB traffic).

#define NB 8
#define NC 64
#define NK 12
#define NP (512 * 512)
#define NPV (NP / 4)   // float4 pixels per (b,c) plane = 65536

__global__ __launch_bounds__(256) void
hier_invert_kernel(const float* __restrict__ in,
                   const float* __restrict__ w,
                   const float* __restrict__ bias,
                   float* __restrict__ out) {
    __shared__ float sw[NC];
    __shared__ float sb[NK];
    const int tid = threadIdx.x;
    if (tid < NC) sw[tid] = w[tid];
    if (tid < NK) sb[tid] = bias[tid];
    __syncthreads();

    const long long t = (long long)blockIdx.x * blockDim.x + tid;  // [0, NB*NPV)
    const int b = (int)(t >> 16);        // t / NPV  (NPV = 65536)
    const int p = (int)(t & (NPV - 1));  // t % NPV

    const float4* __restrict__ in4 =
        (const float4*)in + (long long)b * NC * NPV + p;
    float4* __restrict__ out4 =
        (float4*)out + (long long)b * NK * NPV + p;

    // group boundaries (prefix sums of group sizes), compile-time constants
    constexpr int gs[NK + 1] = {0, 1, 4, 14, 20, 28, 38, 46, 52, 57, 59, 62, 64};

#pragma unroll
    for (int k = 0; k < NK; ++k) {
        const float bk = sb[k];
        float4 acc = make_float4(bk, bk, bk, bk);
#pragma unroll
        for (int c = gs[k]; c < gs[k + 1]; ++c) {
            const float4 v = in4[(long long)c * NPV];
            const float wc = sw[c];
            acc.x += wc * v.x;
            acc.y += wc * v.y;
            acc.z += wc * v.z;
            acc.w += wc * v.w;
        }
        out4[(long long)k * NPV] = acc;
    }
}

extern "C" void kernel_launch(void* const* d_in, const int* in_sizes, int n_in,
                              void* d_out, int out_size, void* d_ws, size_t ws_size,
                              hipStream_t stream) {
    const float* in   = (const float*)d_in[0];   // [8,64,512,512] fp32
    const float* w    = (const float*)d_in[1];   // [64] fp32
    const float* bias = (const float*)d_in[2];   // [12] fp32
    float* out        = (float*)d_out;           // [8,12,512,512] fp32

    const int total_threads = NB * NPV;  // 524288
    const int block = 256;
    const int grid = total_threads / block;  // 2048
    hier_invert_kernel<<<grid, block, 0, stream>>>(in, w, bias, out);
}

// Round 2
// 687.042 us; speedup vs baseline: 1.0174x; 1.0174x over previous
//
#include <hip/hip_runtime.h>

// out[b,k,p] = bias[k] + sum_{c in group k} w[c] * in[b,c,p]
// B=8, C=64, K=12, P=512*512. Pure streaming, memory-bound:
// 537 MB read + 101 MB write = 638 MB  ->  ~101 us floor at 6.3 TB/s.
// v2: nontemporal loads/stores (no reuse -> don't allocate L2/L3),
//     2x float4 per thread for deeper memory pipelining,
//     no LDS (weights/bias are wave-uniform -> scalar loads).

#define NB 8
#define NC 64
#define NK 12
#define NP (512 * 512)
#define NPV (NP / 4)          // float4 per (b,c) plane = 65536
#define F4_PER_THREAD 2
#define BLOCK 256
#define TILE (BLOCK * F4_PER_THREAD)      // 512 float4 per block
#define BLOCKS_PER_B (NPV / TILE)         // 128

typedef float v4f __attribute__((ext_vector_type(4)));

__global__ __launch_bounds__(BLOCK) void
hier_invert_kernel(const float* __restrict__ in,
                   const float* __restrict__ w,
                   const float* __restrict__ bias,
                   float* __restrict__ out) {
    const int tid = threadIdx.x;
    const int b    = blockIdx.x >> 7;            // blockIdx / 128
    const int pblk = (blockIdx.x & 127) << 9;    // (blockIdx % 128) * 512
    const int p = pblk + tid;                    // first float4; second at +BLOCK

    const v4f* __restrict__ in4 =
        (const v4f*)in + (long long)b * NC * NPV + p;
    v4f* __restrict__ out4 =
        (v4f*)out + (long long)b * NK * NPV + p;

    // group boundaries (prefix sums of group sizes), compile-time constants
    constexpr int gs[NK + 1] = {0, 1, 4, 14, 20, 28, 38, 46, 52, 57, 59, 62, 64};

#pragma unroll
    for (int k = 0; k < NK; ++k) {
        const float bk = bias[k];                // uniform -> s_load
        v4f acc0 = {bk, bk, bk, bk};
        v4f acc1 = acc0;
#pragma unroll
        for (int c = gs[k]; c < gs[k + 1]; ++c) {
            const float wc = w[c];               // uniform -> s_load
            const v4f v0 = __builtin_nontemporal_load(&in4[(long long)c * NPV]);
            const v4f v1 = __builtin_nontemporal_load(&in4[(long long)c * NPV + BLOCK]);
            acc0 += wc * v0;
            acc1 += wc * v1;
        }
        __builtin_nontemporal_store(acc0, &out4[(long long)k * NPV]);
        __builtin_nontemporal_store(acc1, &out4[(long long)k * NPV + BLOCK]);
    }
}

extern "C" void kernel_launch(void* const* d_in, const int* in_sizes, int n_in,
                              void* d_out, int out_size, void* d_ws, size_t ws_size,
                              hipStream_t stream) {
    const float* in   = (const float*)d_in[0];   // [8,64,512,512] fp32
    const float* w    = (const float*)d_in[1];   // [64] fp32
    const float* bias = (const float*)d_in[2];   // [12] fp32
    float* out        = (float*)d_out;           // [8,12,512,512] fp32

    const int grid = NB * BLOCKS_PER_B;          // 1024
    hier_invert_kernel<<<grid, BLOCK, 0, stream>>>(in, w, bias, out);
}